// Round 7
// baseline (514.959 us; speedup 1.0000x reference)
//
#include <hip/hip_runtime.h>
#include <hip/hip_bf16.h>
#include <math.h>

#define B_DIM 4096
#define D_IN  2048
#define D_HID 3584
#define D_OUT 2048

typedef __bf16 bf16;
typedef float  floatx4  __attribute__((ext_vector_type(4)));
typedef float  floatx16 __attribute__((ext_vector_type(16)));
typedef bf16   bf16x8   __attribute__((ext_vector_type(8)));
typedef bf16   bf16x4   __attribute__((ext_vector_type(4)));

typedef __attribute__((address_space(1))) const void* gptr1;
typedef __attribute__((address_space(3))) void*       lptr3;

__device__ __forceinline__ void load_lds16(const void* g, void* l) {
    __builtin_amdgcn_global_load_lds((gptr1)g, (lptr3)l, 16, 0, 0);
}

struct HL { bf16 h, l; };
__device__ __forceinline__ HL split2(float v) {
    HL r;
    r.h = (bf16)v;
    r.l = (bf16)(v - (float)r.h);
    return r;
}

// T1 XCD-aware tile remap (bijective for nwg = 512, nwg%8==0).
__device__ __forceinline__ void xcd_tile(int& n0, int& m0) {
    const int d  = (int)(blockIdx.x + gridDim.x * blockIdx.y);
    const int r  = d >> 3;
    const int nx = ((d & 7) << 1) | (r & 1);
    const int my = r >> 1;
    n0 = nx * 128;
    m0 = my * 128;
}

// ---------------------------------------------------------------------------
// Fused prep: one launch, block-uniform branch on blockIdx range.
//   blocks [0, 4096):        vesica  (x -> xo hi/lo)
//   blocks [4096, 5888):     tsplit  (Wfl -> WflT hi/lo, transpose+phase)
//   blocks [5888, 13056):    wcat    (Wm;flip(Wfe) -> Wcat hi/lo, 7168 blocks
//                                     = 4096*448/256 — round-6 bug: had 3584)
// ---------------------------------------------------------------------------
__global__ __launch_bounds__(256) void prep_kernel(const float* __restrict__ x,
                                                   const float* __restrict__ Wfl,
                                                   const float* __restrict__ Wm,
                                                   const float* __restrict__ Wfe,
                                                   bf16* __restrict__ xh,
                                                   bf16* __restrict__ xl,
                                                   bf16* __restrict__ th,
                                                   bf16* __restrict__ tl,
                                                   bf16* __restrict__ wh,
                                                   bf16* __restrict__ wl) {
    __shared__ float tile[64][65];
    const int id = blockIdx.x;
    const int t  = threadIdx.x;

    if (id < 4096) {
        // ---------------- vesica ----------------
        const int b  = id;
        const int bp = (b == 0) ? (B_DIM - 1) : (b - 1);

        const floatx4* xr = (const floatx4*)(x + (size_t)b  * D_IN);
        const floatx4* pr = (const floatx4*)(x + (size_t)bp * D_IN);
        const floatx4 v0 = xr[t * 2], v1 = xr[t * 2 + 1];
        const floatx4 p0 = pr[t * 2], p1 = pr[t * 2 + 1];

        float s = 0.f;
#pragma unroll
        for (int j = 0; j < 4; ++j) {
            const float d0 = v0[j] - p0[j], d1 = v1[j] - p1[j];
            s += d0 * d0 + d1 * d1;
        }
#pragma unroll
        for (int off = 32; off > 0; off >>= 1) s += __shfl_down(s, off, 64);

        float* red = &tile[0][0];
        const int wave = t >> 6, lane = t & 63;
        if (lane == 0) red[wave] = s;
        __syncthreads();
        const float dist = sqrtf(red[0] + red[1] + red[2] + red[3]);
        const float sc   = 1.f + fmaxf(0.f, 1.f - fabsf(dist - 1.f));

        bf16x8 h, l;
#pragma unroll
        for (int j = 0; j < 4; ++j) {
            const HL a  = split2(v0[j] * sc);
            const HL b2 = split2(v1[j] * sc);
            h[j] = a.h;      l[j] = a.l;
            h[4 + j] = b2.h; l[4 + j] = b2.l;
        }
        ((bf16x8*)(xh + (size_t)b * D_IN))[t] = h;
        ((bf16x8*)(xl + (size_t)b * D_IN))[t] = l;

    } else if (id < 4096 + 1792) {
        // ---------------- tsplit ----------------
        const int tb = id - 4096;
        const int d0 = (tb & 31) << 6;   // 32 tiles along d
        const int h0 = (tb >> 5) << 6;   // 56 tiles along h
        const int r  = t >> 4;           // 0..15
        const int cg = (t & 15) << 2;    // 0..60

#pragma unroll
        for (int i = 0; i < 4; ++i) {
            const int hr = r + i * 16;
            const floatx4 v = *(const floatx4*)&Wfl[(size_t)(h0 + hr) * 2048 + d0 + cg];
            tile[hr][cg]     = v[0];
            tile[hr][cg + 1] = v[1];
            tile[hr][cg + 2] = v[2];
            tile[hr][cg + 3] = v[3];
        }
        __syncthreads();

        float pm[4];
#pragma unroll
        for (int j = 0; j < 4; ++j) {
            const int h  = h0 + cg + j;
            const int hm = h & 511;
            float p = 1.f;
            if (hm < 2) {
                const float ph = 0.8975979010256552f * (float)(h >> 9); // 2pi/7*c
                p = (hm == 0) ? cosf(ph) : sinf(ph);
            }
            pm[j] = p;
        }

#pragma unroll
        for (int i = 0; i < 4; ++i) {
            const int dr = r + i * 16;
            bf16x4 hh, ll;
#pragma unroll
            for (int j = 0; j < 4; ++j) {
                const HL u = split2(tile[cg + j][dr] * pm[j]);
                hh[j] = u.h;
                ll[j] = u.l;
            }
            const size_t o = (size_t)(d0 + dr) * 3584 + h0 + cg;
            *(bf16x4*)&th[o] = hh;
            *(bf16x4*)&tl[o] = ll;
        }

    } else {
        // ---------------- wcat ----------------
        const int i = (id - 5888) * 256 + t;        // 0 .. 4096*448-1
        const int o = i / 448;                      // output row
        const int g = i - o * 448;                  // 8-elem group
        bf16x8 h, l;
        if (o < 2048) {
            const float* src = Wm + (size_t)o * 3584 + (size_t)g * 8;
            const floatx4 a = ((const floatx4*)src)[0];
            const floatx4 b = ((const floatx4*)src)[1];
#pragma unroll
            for (int j = 0; j < 4; ++j) {
                const HL u = split2(a[j]);
                const HL v = split2(b[j]);
                h[j] = u.h;     l[j] = u.l;
                h[4 + j] = v.h; l[4 + j] = v.l;
            }
        } else {
            const float* src = Wfe + (size_t)(o - 2048) * 3584 + (size_t)(447 - g) * 8;
            const floatx4 a = ((const floatx4*)src)[0];
            const floatx4 b = ((const floatx4*)src)[1];
#pragma unroll
            for (int j = 0; j < 4; ++j) {
                const HL u = split2(b[3 - j]);   // out[0..3] = src[7..4]
                const HL v = split2(a[3 - j]);   // out[4..7] = src[3..0]
                h[j] = u.h;     l[j] = u.l;
                h[4 + j] = v.h; l[4 + j] = v.l;
            }
        }
        ((bf16x8*)wh)[i] = h;
        ((bf16x8*)wl)[i] = l;
    }
}

// ---------------------------------------------------------------------------
// Single bf16x3 GEMM, C = A @ B^T, bf16 hi/lo out. 128x128 tile, BK=64,
// 64 KB LDS, 2 blocks/CU, XCD remap. 32x32x16 MFMA core:
//   A/B frag: lane reads row (lane&31), k-chunk (lane>>5) -> one 16B chunk
//   (k-layout identical for A and B -> any k-permutation cancels in A@B^T);
//   C/D:      col = lane&31, row = (reg&3) + 8*(reg>>2) + 4*(lane>>5).
// Staging swizzle (verified 0 conflicts): slot q holds logical (r, c) with
// c = (q&7)^(r&7); read slot = (row<<3) | (cb ^ (row&7)).
// ---------------------------------------------------------------------------
__global__ __launch_bounds__(256, 2) void gemm3_single(const bf16* __restrict__ Ah,
                                                       const bf16* __restrict__ Al,
                                                       const bf16* __restrict__ Bh,
                                                       const bf16* __restrict__ Bl,
                                                       bf16* __restrict__ C0,
                                                       bf16* __restrict__ C1,
                                                       int M, int N, int K) {
    __shared__ bf16 sAh[128 * 64], sAl[128 * 64];
    __shared__ bf16 sBh[128 * 64], sBl[128 * 64];

    const int tid  = threadIdx.x;
    const int wave = tid >> 6;
    const int lane = tid & 63;
    int n0, m0;
    xcd_tile(n0, m0);
    const int wm   = wave & 1;
    const int wn   = wave >> 1;

    const floatx16 fz = {0.f,0.f,0.f,0.f,0.f,0.f,0.f,0.f,
                         0.f,0.f,0.f,0.f,0.f,0.f,0.f,0.f};
    floatx16 acc[2][2];
#pragma unroll
    for (int i = 0; i < 2; ++i)
#pragma unroll
        for (int j = 0; j < 2; ++j) acc[i][j] = fz;

    const int l31 = lane & 31;
    const int kh  = lane >> 5;        // k-half within a 16-k step
    const int sw7 = l31 & 7;          // == row & 7 for all fragment rows

    for (int kt = 0; kt < K; kt += 64) {
        // stage: 128 rows x 64 cols = 1024 16B-chunks -> 4 passes x 256 thr
#pragma unroll
        for (int i = 0; i < 4; ++i) {
            const int q = ((i * 4 + wave) << 6) + lane;   // 0..1023 (LDS slot)
            const int r = q >> 3;                         // row 0..127
            const int c = (q & 7) ^ (r & 7);              // swizzled src chunk
            const int e = q << 3;                         // linear LDS dest
            const size_t ga = (size_t)(m0 + r) * K + kt + c * 8;
            const size_t gb = (size_t)(n0 + r) * K + kt + c * 8;
            load_lds16(&Ah[ga], &sAh[e]);
            load_lds16(&Al[ga], &sAl[e]);
            load_lds16(&Bh[gb], &sBh[e]);
            load_lds16(&Bl[gb], &sBl[e]);
        }
        __syncthreads();

#pragma unroll
        for (int ks = 0; ks < 4; ++ks) {                  // 4 x K=16
            const int cb = (ks << 1) + kh;                // logical chunk 0..7
            bf16x8 ah[2], al[2], bh[2], bl[2];
#pragma unroll
            for (int mb = 0; mb < 2; ++mb) {
                const int row = wm * 64 + mb * 32 + l31;
                const int off = ((row << 3) | (cb ^ sw7)) << 3;
                ah[mb] = *(const bf16x8*)&sAh[off];
                al[mb] = *(const bf16x8*)&sAl[off];
            }
#pragma unroll
            for (int nb = 0; nb < 2; ++nb) {
                const int row = wn * 64 + nb * 32 + l31;
                const int off = ((row << 3) | (cb ^ sw7)) << 3;
                bh[nb] = *(const bf16x8*)&sBh[off];
                bl[nb] = *(const bf16x8*)&sBl[off];
            }

#pragma unroll
            for (int mb = 0; mb < 2; ++mb)
#pragma unroll
                for (int nb = 0; nb < 2; ++nb) {
                    acc[mb][nb] = __builtin_amdgcn_mfma_f32_32x32x16_bf16(
                        ah[mb], bh[nb], acc[mb][nb], 0, 0, 0);
                    acc[mb][nb] = __builtin_amdgcn_mfma_f32_32x32x16_bf16(
                        al[mb], bh[nb], acc[mb][nb], 0, 0, 0);
                    acc[mb][nb] = __builtin_amdgcn_mfma_f32_32x32x16_bf16(
                        ah[mb], bl[nb], acc[mb][nb], 0, 0, 0);
                }
        }
        __syncthreads();
    }

#pragma unroll
    for (int mb = 0; mb < 2; ++mb)
#pragma unroll
        for (int nb = 0; nb < 2; ++nb) {
            const int col = n0 + wn * 64 + nb * 32 + l31;
#pragma unroll
            for (int reg = 0; reg < 16; ++reg) {
                const int row = m0 + wm * 64 + mb * 32 +
                                (reg & 3) + ((reg >> 2) << 3) + (kh << 2);
                const size_t idx = (size_t)row * N + col;
                const HL u = split2(acc[mb][nb][reg]);
                C0[idx] = u.h;
                C1[idx] = u.l;
            }
        }
}

// ---------------------------------------------------------------------------
// Dual GEMM (bf16x3): male/female = xo @ {Wcm,Wcf}^T in ONE kernel.
// 128x128 tile, BK=32, 48 KB LDS, 2 blocks/CU, XCD remap. 32x32x16 core.
// Staging swizzle (verified 0 conflicts): slot q holds (r,c) of
// p = q ^ ((q>>3)&7); read slot = ((row<<2)+cb) ^ ((row>>1)&7).
// ---------------------------------------------------------------------------
__global__ __launch_bounds__(256, 2) void gemm3_dual(const bf16* __restrict__ Ah,
                                                     const bf16* __restrict__ Al,
                                                     const bf16* __restrict__ Bmh,
                                                     const bf16* __restrict__ Bml,
                                                     const bf16* __restrict__ Bfh,
                                                     const bf16* __restrict__ Bfl,
                                                     float* __restrict__ Cm,
                                                     float* __restrict__ Cf,
                                                     int M, int N, int K) {
    __shared__ bf16 sAh[4096], sAl[4096];
    __shared__ bf16 sMh[4096], sMl[4096];
    __shared__ bf16 sFh[4096], sFl[4096];

    const int tid  = threadIdx.x;
    const int wave = tid >> 6;
    const int lane = tid & 63;
    int n0, m0;
    xcd_tile(n0, m0);
    const int wm   = wave & 1;
    const int wn   = wave >> 1;

    const floatx16 fz = {0.f,0.f,0.f,0.f,0.f,0.f,0.f,0.f,
                         0.f,0.f,0.f,0.f,0.f,0.f,0.f,0.f};
    floatx16 am[2][2], af[2][2];
#pragma unroll
    for (int i = 0; i < 2; ++i)
#pragma unroll
        for (int j = 0; j < 2; ++j) { am[i][j] = fz; af[i][j] = fz; }

    const int l31 = lane & 31;
    const int kh  = lane >> 5;
    const int rsw = (l31 >> 1) & 7;   // == (row>>1)&7 for all fragment rows

    for (int kt = 0; kt < K; kt += 32) {
#pragma unroll
        for (int i = 0; i < 2; ++i) {
            const int q = ((i * 4 + wave) << 6) + lane;   // 0..511 (LDS slot)
            const int p = q ^ ((q >> 3) & 7);             // swizzled src chunk-id
            const int r = p >> 2, c = p & 3;
            const int e = q << 3;                         // linear LDS dest
            const size_t ga = (size_t)(m0 + r) * K + kt + c * 8;
            const size_t gb = (size_t)(n0 + r) * K + kt + c * 8;
            load_lds16(&Ah[ga],  &sAh[e]);
            load_lds16(&Al[ga],  &sAl[e]);
            load_lds16(&Bmh[gb], &sMh[e]);
            load_lds16(&Bml[gb], &sMl[e]);
            load_lds16(&Bfh[gb], &sFh[e]);
            load_lds16(&Bfl[gb], &sFl[e]);
        }
        __syncthreads();

#pragma unroll
        for (int kk = 0; kk < 2; ++kk) {                  // 2 x K=16
            const int cb = (kk << 1) + kh;                // logical chunk 0..3
            bf16x8 ah[2], al[2];
#pragma unroll
            for (int mb = 0; mb < 2; ++mb) {
                const int row = wm * 64 + mb * 32 + l31;
                const int off = ((((row << 2) + cb) ^ rsw)) << 3;
                ah[mb] = *(const bf16x8*)&sAh[off];
                al[mb] = *(const bf16x8*)&sAl[off];
            }
#pragma unroll
            for (int nb = 0; nb < 2; ++nb) {
                const int row = wn * 64 + nb * 32 + l31;
                const int off = ((((row << 2) + cb) ^ rsw)) << 3;
                const bf16x8 mh = *(const bf16x8*)&sMh[off];
                const bf16x8 ml = *(const bf16x8*)&sMl[off];
                const bf16x8 fh = *(const bf16x8*)&sFh[off];
                const bf16x8 fl = *(const bf16x8*)&sFl[off];
#pragma unroll
                for (int mb = 0; mb < 2; ++mb) {
                    am[mb][nb] = __builtin_amdgcn_mfma_f32_32x32x16_bf16(
                        ah[mb], mh, am[mb][nb], 0, 0, 0);
                    am[mb][nb] = __builtin_amdgcn_mfma_f32_32x32x16_bf16(
                        al[mb], mh, am[mb][nb], 0, 0, 0);
                    am[mb][nb] = __builtin_amdgcn_mfma_f32_32x32x16_bf16(
                        ah[mb], ml, am[mb][nb], 0, 0, 0);
                    af[mb][nb] = __builtin_amdgcn_mfma_f32_32x32x16_bf16(
                        ah[mb], fh, af[mb][nb], 0, 0, 0);
                    af[mb][nb] = __builtin_amdgcn_mfma_f32_32x32x16_bf16(
                        al[mb], fh, af[mb][nb], 0, 0, 0);
                    af[mb][nb] = __builtin_amdgcn_mfma_f32_32x32x16_bf16(
                        ah[mb], fl, af[mb][nb], 0, 0, 0);
                }
            }
        }
        __syncthreads();
    }

#pragma unroll
    for (int mb = 0; mb < 2; ++mb)
#pragma unroll
        for (int nb = 0; nb < 2; ++nb) {
            const int col = n0 + wn * 64 + nb * 32 + l31;
#pragma unroll
            for (int reg = 0; reg < 16; ++reg) {
                const int row = m0 + wm * 64 + mb * 32 +
                                (reg & 3) + ((reg >> 2) << 3) + (kh << 2);
                const size_t idx = (size_t)row * N + col;
                Cm[idx] = am[mb][nb][reg];
                Cf[idx] = af[mb][nb][reg];
            }
        }
}

// ---------------------------------------------------------------------------
// Combine: phase_lock = sigmoid(male . female); out = pl*male + (1-pl)*female
// ---------------------------------------------------------------------------
__global__ __launch_bounds__(256) void combine_kernel(const float* __restrict__ male,
                                                      const float* __restrict__ female,
                                                      float* __restrict__ out) {
    const int b = blockIdx.x;
    const int t = threadIdx.x;

    const floatx4* m4 = (const floatx4*)(male   + (size_t)b * D_OUT);
    const floatx4* f4 = (const floatx4*)(female + (size_t)b * D_OUT);
    const floatx4 mv0 = m4[t * 2], mv1 = m4[t * 2 + 1];
    const floatx4 fv0 = f4[t * 2], fv1 = f4[t * 2 + 1];

    float s = 0.f;
#pragma unroll
    for (int j = 0; j < 4; ++j) s += mv0[j] * fv0[j] + mv1[j] * fv1[j];
#pragma unroll
    for (int off = 32; off > 0; off >>= 1) s += __shfl_down(s, off, 64);

    __shared__ float red[4];
    const int wave = t >> 6, lane = t & 63;
    if (lane == 0) red[wave] = s;
    __syncthreads();
    const float dot = red[0] + red[1] + red[2] + red[3];
    const float pl  = 1.f / (1.f + expf(-dot));

    floatx4 o0, o1;
#pragma unroll
    for (int j = 0; j < 4; ++j) {
        o0[j] = pl * mv0[j] + (1.f - pl) * fv0[j];
        o1[j] = pl * mv1[j] + (1.f - pl) * fv1[j];
    }
    floatx4* o4 = (floatx4*)(out + (size_t)b * D_OUT);
    o4[t * 2]     = o0;
    o4[t * 2 + 1] = o1;
}

// ---------------------------------------------------------------------------
// Pipeline:  male = xo @ (Wm P Wfl)^T,  female = xo @ (Wfe_flip P Wfl)^T
// ---------------------------------------------------------------------------
extern "C" void kernel_launch(void* const* d_in, const int* in_sizes, int n_in,
                              void* d_out, int out_size, void* d_ws, size_t ws_size,
                              hipStream_t stream) {
    const float* x   = (const float*)d_in[0];
    const float* Wfl = (const float*)d_in[1]; // [7,512,2048] == [3584,2048]
    const float* Wm  = (const float*)d_in[2]; // [2048,3584]
    const float* Wfe = (const float*)d_in[3]; // [2048,3584]
    float* out = (float*)d_out;
    (void)in_sizes; (void)n_in; (void)out_size; (void)ws_size;

    char* ws = (char*)d_ws;
    bf16*  xo_hi   = (bf16*)(ws);                    // 4096x2048 = 16,777,216
    bf16*  xo_lo   = (bf16*)(ws + 16777216);         // 16,777,216
    bf16*  Wc_hi   = (bf16*)(ws + 33554432);         // 4096x2048 = 16,777,216
    bf16*  Wc_lo   = (bf16*)(ws + 50331648);         // 16,777,216 -> 67,108,864
    // overlay phase A (dead after gemm3_single):
    bf16*  WflT_hi = (bf16*)(ws + 67108864);         // 2048x3584 = 14,680,064
    bf16*  WflT_lo = (bf16*)(ws + 81788928);         // -> 96,468,992
    bf16*  Wcat_hi = (bf16*)(ws + 96468992);         // 4096x3584 = 29,360,128
    bf16*  Wcat_lo = (bf16*)(ws + 125829120);        // -> 155,189,248
    // overlay phase B (after gemm3_single):
    float* male    = (float*)(ws + 67108864);        // 4096x2048 f32 = 33,554,432
    float* female  = (float*)(ws + 100663296);       // -> 134,217,728

    // 1. fused prep: vesica(4096) + tsplit(1792) + wcat(7168) = 13056 blocks
    prep_kernel<<<13056, 256, 0, stream>>>(x, Wfl, Wm, Wfe,
                                           xo_hi, xo_lo,
                                           WflT_hi, WflT_lo,
                                           Wcat_hi, Wcat_lo);

    // 2. weight combine: Wc[4096,2048] = Wcat @ WflT^T  (K=3584, BK=64)
    gemm3_single<<<dim3(D_IN / 128, (2 * D_OUT) / 128), 256, 0, stream>>>(
        Wcat_hi, Wcat_lo, WflT_hi, WflT_lo, Wc_hi, Wc_lo,
        2 * D_OUT, D_IN, D_HID);

    // 3. main dual GEMM: male/female = xo @ Wc^T  (K=2048, fp32 out)
    gemm3_dual<<<dim3(D_OUT / 128, B_DIM / 128), 256, 0, stream>>>(
        xo_hi, xo_lo,
        Wc_hi, Wc_lo,
        Wc_hi + (size_t)D_OUT * D_IN, Wc_lo + (size_t)D_OUT * D_IN,
        male, female, B_DIM, D_OUT, D_IN);

    // 4. sigmoid phase-lock blend (fp32 out)
    combine_kernel<<<B_DIM, 256, 0, stream>>>(male, female, out);
}

// Round 8
// 485.521 us; speedup vs baseline: 1.0606x; 1.0606x over previous
//
#include <hip/hip_runtime.h>
#include <hip/hip_bf16.h>
#include <math.h>

#define B_DIM 4096
#define D_IN  2048
#define D_HID 3584
#define D_OUT 2048

typedef __bf16 bf16;
typedef float  floatx4 __attribute__((ext_vector_type(4)));
typedef bf16   bf16x8  __attribute__((ext_vector_type(8)));
typedef bf16   bf16x4  __attribute__((ext_vector_type(4)));

typedef __attribute__((address_space(1))) const void* gptr1;
typedef __attribute__((address_space(3))) void*       lptr3;

__device__ __forceinline__ void load_lds16(const void* g, void* l) {
    __builtin_amdgcn_global_load_lds((gptr1)g, (lptr3)l, 16, 0, 0);
}

struct HL { bf16 h, l; };
__device__ __forceinline__ HL split2(float v) {
    HL r;
    r.h = (bf16)v;
    r.l = (bf16)(v - (float)r.h);
    return r;
}

// T1 XCD-aware tile remap (bijective for nwg = 512, nwg%8==0).
__device__ __forceinline__ void xcd_tile(int& n0, int& m0) {
    const int d  = (int)(blockIdx.x + gridDim.x * blockIdx.y);
    const int r  = d >> 3;
    const int nx = ((d & 7) << 1) | (r & 1);
    const int my = r >> 1;
    n0 = nx * 128;
    m0 = my * 128;
}

// ---------------------------------------------------------------------------
// Fused prep: one launch, block-uniform branch on blockIdx range.
//   blocks [0, 4096):        vesica  (x -> xo hi/lo)
//   blocks [4096, 5888):     tsplit  (Wfl -> WflT hi/lo, transpose+phase)
//   blocks [5888, 13056):    wcat    (Wm;flip(Wfe) -> Wcat hi/lo)
// (verified correct in round 7)
// ---------------------------------------------------------------------------
__global__ __launch_bounds__(256) void prep_kernel(const float* __restrict__ x,
                                                   const float* __restrict__ Wfl,
                                                   const float* __restrict__ Wm,
                                                   const float* __restrict__ Wfe,
                                                   bf16* __restrict__ xh,
                                                   bf16* __restrict__ xl,
                                                   bf16* __restrict__ th,
                                                   bf16* __restrict__ tl,
                                                   bf16* __restrict__ wh,
                                                   bf16* __restrict__ wl) {
    __shared__ float tile[64][65];
    const int id = blockIdx.x;
    const int t  = threadIdx.x;

    if (id < 4096) {
        // ---------------- vesica ----------------
        const int b  = id;
        const int bp = (b == 0) ? (B_DIM - 1) : (b - 1);

        const floatx4* xr = (const floatx4*)(x + (size_t)b  * D_IN);
        const floatx4* pr = (const floatx4*)(x + (size_t)bp * D_IN);
        const floatx4 v0 = xr[t * 2], v1 = xr[t * 2 + 1];
        const floatx4 p0 = pr[t * 2], p1 = pr[t * 2 + 1];

        float s = 0.f;
#pragma unroll
        for (int j = 0; j < 4; ++j) {
            const float d0 = v0[j] - p0[j], d1 = v1[j] - p1[j];
            s += d0 * d0 + d1 * d1;
        }
#pragma unroll
        for (int off = 32; off > 0; off >>= 1) s += __shfl_down(s, off, 64);

        float* red = &tile[0][0];
        const int wave = t >> 6, lane = t & 63;
        if (lane == 0) red[wave] = s;
        __syncthreads();
        const float dist = sqrtf(red[0] + red[1] + red[2] + red[3]);
        const float sc   = 1.f + fmaxf(0.f, 1.f - fabsf(dist - 1.f));

        bf16x8 h, l;
#pragma unroll
        for (int j = 0; j < 4; ++j) {
            const HL a  = split2(v0[j] * sc);
            const HL b2 = split2(v1[j] * sc);
            h[j] = a.h;      l[j] = a.l;
            h[4 + j] = b2.h; l[4 + j] = b2.l;
        }
        ((bf16x8*)(xh + (size_t)b * D_IN))[t] = h;
        ((bf16x8*)(xl + (size_t)b * D_IN))[t] = l;

    } else if (id < 4096 + 1792) {
        // ---------------- tsplit ----------------
        const int tb = id - 4096;
        const int d0 = (tb & 31) << 6;   // 32 tiles along d
        const int h0 = (tb >> 5) << 6;   // 56 tiles along h
        const int r  = t >> 4;           // 0..15
        const int cg = (t & 15) << 2;    // 0..60

#pragma unroll
        for (int i = 0; i < 4; ++i) {
            const int hr = r + i * 16;
            const floatx4 v = *(const floatx4*)&Wfl[(size_t)(h0 + hr) * 2048 + d0 + cg];
            tile[hr][cg]     = v[0];
            tile[hr][cg + 1] = v[1];
            tile[hr][cg + 2] = v[2];
            tile[hr][cg + 3] = v[3];
        }
        __syncthreads();

        float pm[4];
#pragma unroll
        for (int j = 0; j < 4; ++j) {
            const int h  = h0 + cg + j;
            const int hm = h & 511;
            float p = 1.f;
            if (hm < 2) {
                const float ph = 0.8975979010256552f * (float)(h >> 9); // 2pi/7*c
                p = (hm == 0) ? cosf(ph) : sinf(ph);
            }
            pm[j] = p;
        }

#pragma unroll
        for (int i = 0; i < 4; ++i) {
            const int dr = r + i * 16;
            bf16x4 hh, ll;
#pragma unroll
            for (int j = 0; j < 4; ++j) {
                const HL u = split2(tile[cg + j][dr] * pm[j]);
                hh[j] = u.h;
                ll[j] = u.l;
            }
            const size_t o = (size_t)(d0 + dr) * 3584 + h0 + cg;
            *(bf16x4*)&th[o] = hh;
            *(bf16x4*)&tl[o] = ll;
        }

    } else {
        // ---------------- wcat ----------------
        const int i = (id - 5888) * 256 + t;        // 0 .. 4096*448-1
        const int o = i / 448;                      // output row
        const int g = i - o * 448;                  // 8-elem group
        bf16x8 h, l;
        if (o < 2048) {
            const float* src = Wm + (size_t)o * 3584 + (size_t)g * 8;
            const floatx4 a = ((const floatx4*)src)[0];
            const floatx4 b = ((const floatx4*)src)[1];
#pragma unroll
            for (int j = 0; j < 4; ++j) {
                const HL u = split2(a[j]);
                const HL v = split2(b[j]);
                h[j] = u.h;     l[j] = u.l;
                h[4 + j] = v.h; l[4 + j] = v.l;
            }
        } else {
            const float* src = Wfe + (size_t)(o - 2048) * 3584 + (size_t)(447 - g) * 8;
            const floatx4 a = ((const floatx4*)src)[0];
            const floatx4 b = ((const floatx4*)src)[1];
#pragma unroll
            for (int j = 0; j < 4; ++j) {
                const HL u = split2(b[3 - j]);   // out[0..3] = src[7..4]
                const HL v = split2(a[3 - j]);   // out[4..7] = src[3..0]
                h[j] = u.h;     l[j] = u.l;
                h[4 + j] = v.h; l[4 + j] = v.l;
            }
        }
        ((bf16x8*)wh)[i] = h;
        ((bf16x8*)wl)[i] = l;
    }
}

// ---------------------------------------------------------------------------
// Single bf16x3 GEMM, C = A @ B^T, bf16 hi/lo out. 128x128 tile, BK=64:
// 96 MFMA per wave per barrier-pair, 64 KB LDS, 2 blocks/CU.
// ROUND-5 VERBATIM (measured 0 bank conflicts) + T1 XCD tile remap.
// ---------------------------------------------------------------------------
__global__ __launch_bounds__(256, 2) void gemm3_single(const bf16* __restrict__ Ah,
                                                       const bf16* __restrict__ Al,
                                                       const bf16* __restrict__ Bh,
                                                       const bf16* __restrict__ Bl,
                                                       bf16* __restrict__ C0,
                                                       bf16* __restrict__ C1,
                                                       int M, int N, int K) {
    __shared__ bf16 sAh[128 * 64], sAl[128 * 64];
    __shared__ bf16 sBh[128 * 64], sBl[128 * 64];

    const int tid  = threadIdx.x;
    const int wave = tid >> 6;
    const int lane = tid & 63;
    int n0, m0;
    xcd_tile(n0, m0);
    const int wm   = wave & 1;
    const int wn   = wave >> 1;

    floatx4 acc[4][4];
#pragma unroll
    for (int i = 0; i < 4; ++i)
#pragma unroll
        for (int j = 0; j < 4; ++j) acc[i][j] = (floatx4){0.f, 0.f, 0.f, 0.f};

    const int lr  = lane & 15;
    const int cc8 = (lane >> 4) << 3;
    const int sw  = lr & 7;           // == row & 7 for all fragment rows

    for (int kt = 0; kt < K; kt += 64) {
        // each tile: 128 rows x 64 cols = 1024 16B-chunks -> 4 passes x 256 thr
#pragma unroll
        for (int i = 0; i < 4; ++i) {
            const int q = ((i * 4 + wave) << 6) + lane;   // 0..1023 (LDS slot)
            const int r = q >> 3;                         // row 0..127
            const int c = (q & 7) ^ (r & 7);              // swizzled src chunk
            const int e = q << 3;                         // linear LDS dest
            const size_t ga = (size_t)(m0 + r) * K + kt + c * 8;
            const size_t gb = (size_t)(n0 + r) * K + kt + c * 8;
            load_lds16(&Ah[ga], &sAh[e]);
            load_lds16(&Al[ga], &sAl[e]);
            load_lds16(&Bh[gb], &sBh[e]);
            load_lds16(&Bl[gb], &sBl[e]);
        }
        __syncthreads();

#pragma unroll
        for (int ks = 0; ks < 2; ++ks) {
            const int cb = (ks << 2) + (cc8 >> 3);        // logical chunk 0..7
            const int co = (cb ^ sw) << 3;                // swizzled elem off
            bf16x8 ah[4], al[4], bh[4], bl[4];
#pragma unroll
            for (int mi = 0; mi < 4; ++mi) {
                const int off = ((wm * 64 + mi * 16 + lr) << 6) + co;
                ah[mi] = *(const bf16x8*)&sAh[off];
                al[mi] = *(const bf16x8*)&sAl[off];
            }
#pragma unroll
            for (int ni = 0; ni < 4; ++ni) {
                const int off = ((wn * 64 + ni * 16 + lr) << 6) + co;
                bh[ni] = *(const bf16x8*)&sBh[off];
                bl[ni] = *(const bf16x8*)&sBl[off];
            }

#pragma unroll
            for (int mi = 0; mi < 4; ++mi)
#pragma unroll
                for (int ni = 0; ni < 4; ++ni) {
                    acc[mi][ni] = __builtin_amdgcn_mfma_f32_16x16x32_bf16(
                        ah[mi], bh[ni], acc[mi][ni], 0, 0, 0);
                    acc[mi][ni] = __builtin_amdgcn_mfma_f32_16x16x32_bf16(
                        al[mi], bh[ni], acc[mi][ni], 0, 0, 0);
                    acc[mi][ni] = __builtin_amdgcn_mfma_f32_16x16x32_bf16(
                        ah[mi], bl[ni], acc[mi][ni], 0, 0, 0);
                }
        }
        __syncthreads();
    }

    const int rq = (lane >> 4) << 2;
    const int cl = lane & 15;
#pragma unroll
    for (int mi = 0; mi < 4; ++mi) {
#pragma unroll
        for (int ni = 0; ni < 4; ++ni) {
            const int col = n0 + wn * 64 + ni * 16 + cl;
#pragma unroll
            for (int r = 0; r < 4; ++r) {
                const int row = m0 + wm * 64 + mi * 16 + rq + r;
                const size_t idx = (size_t)row * N + col;
                const HL u = split2(acc[mi][ni][r]);
                C0[idx] = u.h;
                C1[idx] = u.l;
            }
        }
    }
}

// ---------------------------------------------------------------------------
// Dual GEMM (bf16x3): male = xo @ Wcm^T, female = xo @ Wcf^T in ONE kernel —
// A-tiles staged once for both products. 6 LDS tiles (48 KB), fp32 out.
// ROUND-5 VERBATIM (measured 0 bank conflicts) + T1 XCD tile remap.
// ---------------------------------------------------------------------------
__global__ __launch_bounds__(256, 2) void gemm3_dual(const bf16* __restrict__ Ah,
                                                     const bf16* __restrict__ Al,
                                                     const bf16* __restrict__ Bmh,
                                                     const bf16* __restrict__ Bml,
                                                     const bf16* __restrict__ Bfh,
                                                     const bf16* __restrict__ Bfl,
                                                     float* __restrict__ Cm,
                                                     float* __restrict__ Cf,
                                                     int M, int N, int K) {
    __shared__ bf16 sAh[4096], sAl[4096];
    __shared__ bf16 sMh[4096], sMl[4096];
    __shared__ bf16 sFh[4096], sFl[4096];

    const int tid  = threadIdx.x;
    const int wave = tid >> 6;
    const int lane = tid & 63;
    int n0, m0;
    xcd_tile(n0, m0);
    const int wm   = wave & 1;
    const int wn   = wave >> 1;

    floatx4 am[4][4], af[4][4];
#pragma unroll
    for (int i = 0; i < 4; ++i)
#pragma unroll
        for (int j = 0; j < 4; ++j) {
            am[i][j] = (floatx4){0.f, 0.f, 0.f, 0.f};
            af[i][j] = (floatx4){0.f, 0.f, 0.f, 0.f};
        }

    const int lr  = lane & 15;
    const int cc8 = (lane >> 4) << 3;
    const int cq  = cc8 >> 3;         // logical chunk 0..3
    const int hsw = lr >> 1;          // == (row>>1)&7 for all fragment rows

    for (int kt = 0; kt < K; kt += 32) {
#pragma unroll
        for (int i = 0; i < 2; ++i) {
            const int q = ((i * 4 + wave) << 6) + lane;   // 0..511 (LDS slot)
            const int p = q ^ ((q >> 3) & 7);             // swizzled src chunk-id
            const int r = p >> 2, c = p & 3;
            const int e = q << 3;                         // linear LDS dest
            const size_t ga = (size_t)(m0 + r) * K + kt + c * 8;
            const size_t gb = (size_t)(n0 + r) * K + kt + c * 8;
            load_lds16(&Ah[ga],  &sAh[e]);
            load_lds16(&Al[ga],  &sAl[e]);
            load_lds16(&Bmh[gb], &sMh[e]);
            load_lds16(&Bml[gb], &sMl[e]);
            load_lds16(&Bfh[gb], &sFh[e]);
            load_lds16(&Bfl[gb], &sFl[e]);
        }
        __syncthreads();

        bf16x8 ah[4], al[4];
#pragma unroll
        for (int mi = 0; mi < 4; ++mi) {
            const int ql  = ((wm * 64 + mi * 16 + lr) << 2) + cq;
            const int off = (ql ^ hsw) << 3;
            ah[mi] = *(const bf16x8*)&sAh[off];
            al[mi] = *(const bf16x8*)&sAl[off];
        }
#pragma unroll
        for (int ni = 0; ni < 4; ++ni) {
            const int ql  = ((wn * 64 + ni * 16 + lr) << 2) + cq;
            const int off = (ql ^ hsw) << 3;
            const bf16x8 mh = *(const bf16x8*)&sMh[off];
            const bf16x8 ml = *(const bf16x8*)&sMl[off];
            const bf16x8 fh = *(const bf16x8*)&sFh[off];
            const bf16x8 fl = *(const bf16x8*)&sFl[off];
#pragma unroll
            for (int mi = 0; mi < 4; ++mi) {
                am[mi][ni] = __builtin_amdgcn_mfma_f32_16x16x32_bf16(
                    ah[mi], mh, am[mi][ni], 0, 0, 0);
                am[mi][ni] = __builtin_amdgcn_mfma_f32_16x16x32_bf16(
                    al[mi], mh, am[mi][ni], 0, 0, 0);
                am[mi][ni] = __builtin_amdgcn_mfma_f32_16x16x32_bf16(
                    ah[mi], ml, am[mi][ni], 0, 0, 0);
                af[mi][ni] = __builtin_amdgcn_mfma_f32_16x16x32_bf16(
                    ah[mi], fh, af[mi][ni], 0, 0, 0);
                af[mi][ni] = __builtin_amdgcn_mfma_f32_16x16x32_bf16(
                    al[mi], fh, af[mi][ni], 0, 0, 0);
                af[mi][ni] = __builtin_amdgcn_mfma_f32_16x16x32_bf16(
                    ah[mi], fl, af[mi][ni], 0, 0, 0);
            }
        }
        __syncthreads();
    }

    const int rq = (lane >> 4) << 2;
    const int cl = lane & 15;
#pragma unroll
    for (int mi = 0; mi < 4; ++mi) {
#pragma unroll
        for (int ni = 0; ni < 4; ++ni) {
            const int col = n0 + wn * 64 + ni * 16 + cl;
#pragma unroll
            for (int r = 0; r < 4; ++r) {
                const int row = m0 + wm * 64 + mi * 16 + rq + r;
                const size_t idx = (size_t)row * N + col;
                Cm[idx] = am[mi][ni][r];
                Cf[idx] = af[mi][ni][r];
            }
        }
    }
}

// ---------------------------------------------------------------------------
// Combine: phase_lock = sigmoid(male . female); out = pl*male + (1-pl)*female
// ---------------------------------------------------------------------------
__global__ __launch_bounds__(256) void combine_kernel(const float* __restrict__ male,
                                                      const float* __restrict__ female,
                                                      float* __restrict__ out) {
    const int b = blockIdx.x;
    const int t = threadIdx.x;

    const floatx4* m4 = (const floatx4*)(male   + (size_t)b * D_OUT);
    const floatx4* f4 = (const floatx4*)(female + (size_t)b * D_OUT);
    const floatx4 mv0 = m4[t * 2], mv1 = m4[t * 2 + 1];
    const floatx4 fv0 = f4[t * 2], fv1 = f4[t * 2 + 1];

    float s = 0.f;
#pragma unroll
    for (int j = 0; j < 4; ++j) s += mv0[j] * fv0[j] + mv1[j] * fv1[j];
#pragma unroll
    for (int off = 32; off > 0; off >>= 1) s += __shfl_down(s, off, 64);

    __shared__ float red[4];
    const int wave = t >> 6, lane = t & 63;
    if (lane == 0) red[wave] = s;
    __syncthreads();
    const float dot = red[0] + red[1] + red[2] + red[3];
    const float pl  = 1.f / (1.f + expf(-dot));

    floatx4 o0, o1;
#pragma unroll
    for (int j = 0; j < 4; ++j) {
        o0[j] = pl * mv0[j] + (1.f - pl) * fv0[j];
        o1[j] = pl * mv1[j] + (1.f - pl) * fv1[j];
    }
    floatx4* o4 = (floatx4*)(out + (size_t)b * D_OUT);
    o4[t * 2]     = o0;
    o4[t * 2 + 1] = o1;
}

// ---------------------------------------------------------------------------
// Pipeline:  male = xo @ (Wm P Wfl)^T,  female = xo @ (Wfe_flip P Wfl)^T
// ---------------------------------------------------------------------------
extern "C" void kernel_launch(void* const* d_in, const int* in_sizes, int n_in,
                              void* d_out, int out_size, void* d_ws, size_t ws_size,
                              hipStream_t stream) {
    const float* x   = (const float*)d_in[0];
    const float* Wfl = (const float*)d_in[1]; // [7,512,2048] == [3584,2048]
    const float* Wm  = (const float*)d_in[2]; // [2048,3584]
    const float* Wfe = (const float*)d_in[3]; // [2048,3584]
    float* out = (float*)d_out;
    (void)in_sizes; (void)n_in; (void)out_size; (void)ws_size;

    char* ws = (char*)d_ws;
    bf16*  xo_hi   = (bf16*)(ws);                    // 4096x2048 = 16,777,216
    bf16*  xo_lo   = (bf16*)(ws + 16777216);         // 16,777,216
    bf16*  Wc_hi   = (bf16*)(ws + 33554432);         // 4096x2048 = 16,777,216
    bf16*  Wc_lo   = (bf16*)(ws + 50331648);         // 16,777,216 -> 67,108,864
    // overlay phase A (dead after gemm3_single):
    bf16*  WflT_hi = (bf16*)(ws + 67108864);         // 2048x3584 = 14,680,064
    bf16*  WflT_lo = (bf16*)(ws + 81788928);         // -> 96,468,992
    bf16*  Wcat_hi = (bf16*)(ws + 96468992);         // 4096x3584 = 29,360,128
    bf16*  Wcat_lo = (bf16*)(ws + 125829120);        // -> 155,189,248
    // overlay phase B (after gemm3_single):
    float* male    = (float*)(ws + 67108864);        // 4096x2048 f32 = 33,554,432
    float* female  = (float*)(ws + 100663296);       // -> 134,217,728

    // 1. fused prep: vesica(4096) + tsplit(1792) + wcat(7168) = 13056 blocks
    prep_kernel<<<13056, 256, 0, stream>>>(x, Wfl, Wm, Wfe,
                                           xo_hi, xo_lo,
                                           WflT_hi, WflT_lo,
                                           Wcat_hi, Wcat_lo);

    // 2. weight combine: Wc[4096,2048] = Wcat @ WflT^T  (K=3584, BK=64)
    gemm3_single<<<dim3(D_IN / 128, (2 * D_OUT) / 128), 256, 0, stream>>>(
        Wcat_hi, Wcat_lo, WflT_hi, WflT_lo, Wc_hi, Wc_lo,
        2 * D_OUT, D_IN, D_HID);

    // 3. main dual GEMM: male/female = xo @ Wc^T  (K=2048, fp32 out)
    gemm3_dual<<<dim3(D_OUT / 128, B_DIM / 128), 256, 0, stream>>>(
        xo_hi, xo_lo,
        Wc_hi, Wc_lo,
        Wc_hi + (size_t)D_OUT * D_IN, Wc_lo + (size_t)D_OUT * D_IN,
        male, female, B_DIM, D_OUT, D_IN);

    // 4. sigmoid phase-lock blend (fp32 out)
    combine_kernel<<<B_DIM, 256, 0, stream>>>(male, female, out);
}